// Round 9
// baseline (13096.600 us; speedup 1.0000x reference)
//
#include <hip/hip_runtime.h>
#include <hip/hip_bf16.h>

#define D_MODEL 1024
#define N_HEADS 16
#define DH 64
#define CHUNK_LEN 50
#define MEM_LEN 16
#define TT 66            // MEM_LEN + CHUNK_LEN
#define BB 64
#define LL 2000
#define NCHUNK 40
#define MTOK (BB*TT)     // 4224
#define MROW (BB*MEM_LEN) // 1024
#define MALLR ((size_t)BB*LL) // 128000 chunk-token rows

typedef _Float16 half8_t __attribute__((ext_vector_type(8)));
typedef __attribute__((ext_vector_type(4))) float f32x4;

typedef __attribute__((address_space(1))) const void GVoid;
typedef __attribute__((address_space(3))) void LVoid;

__device__ __forceinline__ void gload16(const void* g, void* l) {
  __builtin_amdgcn_global_load_lds((GVoid*)g, (LVoid*)l, 16, 0, 0);
}

// ---------------- weight fp32 -> fp16 ----------------
__global__ __launch_bounds__(256) void f2h_kernel(const float* __restrict__ in,
                                                  _Float16* __restrict__ out, int n) {
  int i = (blockIdx.x * 256 + threadIdx.x) * 4;
  if (i < n) {
    float4 v = *(const float4*)(in + i);
    out[i+0] = (_Float16)v.x;
    out[i+1] = (_Float16)v.y;
    out[i+2] = (_Float16)v.z;
    out[i+3] = (_Float16)v.w;
  }
}

// ---------------- shared LN row body ----------------
__device__ __forceinline__ void ln_row(float4 v, int tid, int d,
                                       const float* gam, const float* bet,
                                       _Float16* o) {
  float sum = v.x+v.y+v.z+v.w;
  float sq  = v.x*v.x+v.y*v.y+v.z*v.z+v.w*v.w;
  #pragma unroll
  for (int off = 32; off; off >>= 1) {
    sum += __shfl_down(sum, off, 64);
    sq  += __shfl_down(sq,  off, 64);
  }
  __shared__ float rs_[4], rq_[4];
  int wave = tid >> 6, lane = tid & 63;
  if (lane == 0) { rs_[wave] = sum; rq_[wave] = sq; }
  __syncthreads();
  sum = rs_[0]+rs_[1]+rs_[2]+rs_[3];
  sq  = rq_[0]+rq_[1]+rq_[2]+rq_[3];
  float mu  = sum * (1.0f/D_MODEL);
  float var = sq  * (1.0f/D_MODEL) - mu*mu;
  float rstd = rsqrtf(var + 1e-5f);
  float4 gv = *(const float4*)(gam + d);
  float4 bv = *(const float4*)(bet + d);
  o[0] = (_Float16)((v.x-mu)*rstd*gv.x + bv.x);
  o[1] = (_Float16)((v.y-mu)*rstd*gv.y + bv.y);
  o[2] = (_Float16)((v.z-mu)*rstd*gv.z + bv.z);
  o[3] = (_Float16)((v.w-mu)*rstd*gv.w + bv.w);
}

// ---------------- fallback: build z (all rows) + LN1 ----------------
__global__ __launch_bounds__(256) void build_z_ln(
    const int* __restrict__ in_prob, const int* __restrict__ in_skill,
    const float* __restrict__ emb_p, const float* __restrict__ emb_s,
    const float* __restrict__ mem_src, int mem_bstride,
    const float* __restrict__ pos,
    const float* __restrict__ gam, const float* __restrict__ bet,
    float* __restrict__ z, _Float16* __restrict__ zn, int chunk)
{
  int row = blockIdx.x;
  int b = row / TT, t = row % TT;
  int tid = threadIdx.x;
  int d = tid * 4;
  float4 v;
  if (t < MEM_LEN) {
    v = *(const float4*)(mem_src + (size_t)b*mem_bstride + t*D_MODEL + d);
  } else {
    int tok = chunk*CHUNK_LEN + (t - MEM_LEN);
    int p = in_prob[b*LL + tok];
    int s = in_skill[b*LL + tok];
    float4 vp = *(const float4*)(emb_p + (size_t)p*D_MODEL + d);
    float4 vs = *(const float4*)(emb_s + (size_t)s*D_MODEL + d);
    v = make_float4(vp.x+vs.x, vp.y+vs.y, vp.z+vs.z, vp.w+vs.w);
  }
  float4 pv = *(const float4*)(pos + t*D_MODEL + d);
  v.x += pv.x; v.y += pv.y; v.z += pv.z; v.w += pv.w;
  *(float4*)(z + (size_t)row*D_MODEL + d) = v;
  ln_row(v, tid, d, gam, bet, zn + (size_t)row*D_MODEL + d);
}

// ---------------- tail mode: build zn (all rows) + z_mem (compact mem rows) ----------------
__global__ __launch_bounds__(256) void build_z_ln_lite(
    const int* __restrict__ in_prob, const int* __restrict__ in_skill,
    const float* __restrict__ emb_p, const float* __restrict__ emb_s,
    const float* __restrict__ mem_src, int mem_bstride,
    const float* __restrict__ pos,
    const float* __restrict__ gam, const float* __restrict__ bet,
    float* __restrict__ z_mem, _Float16* __restrict__ zn, int chunk)
{
  int row = blockIdx.x;
  int b = row / TT, t = row % TT;
  int tid = threadIdx.x;
  int d = tid * 4;
  float4 v;
  if (t < MEM_LEN) {
    v = *(const float4*)(mem_src + (size_t)b*mem_bstride + t*D_MODEL + d);
  } else {
    int tok = chunk*CHUNK_LEN + (t - MEM_LEN);
    int p = in_prob[b*LL + tok];
    int s = in_skill[b*LL + tok];
    float4 vp = *(const float4*)(emb_p + (size_t)p*D_MODEL + d);
    float4 vs = *(const float4*)(emb_s + (size_t)s*D_MODEL + d);
    v = make_float4(vp.x+vs.x, vp.y+vs.y, vp.z+vs.z, vp.w+vs.w);
  }
  float4 pv = *(const float4*)(pos + t*D_MODEL + d);
  v.x += pv.x; v.y += pv.y; v.z += pv.z; v.w += pv.w;
  if (t < MEM_LEN)
    *(float4*)(z_mem + ((size_t)b*MEM_LEN + t)*D_MODEL + d) = v;
  ln_row(v, tid, d, gam, bet, zn + (size_t)row*D_MODEL + d);
}

// ---------------- tail: build z-base (emb+pos) for a row group ----------------
__global__ __launch_bounds__(256) void build_zbase_group(
    const int* __restrict__ in_prob, const int* __restrict__ in_skill,
    const float* __restrict__ emb_p, const float* __restrict__ emb_s,
    const float* __restrict__ pos,
    float* __restrict__ zf, size_t r0)
{
  size_t rg = r0 + blockIdx.x;       // global token row: b*LL + tok
  int b = (int)(rg / LL);
  int tok = (int)(rg - (size_t)b*LL);
  int t = MEM_LEN + (tok % CHUNK_LEN);
  int tid = threadIdx.x;
  int d = tid * 4;
  int p = in_prob[rg];
  int s = in_skill[rg];
  float4 vp = *(const float4*)(emb_p + (size_t)p*D_MODEL + d);
  float4 vs = *(const float4*)(emb_s + (size_t)s*D_MODEL + d);
  float4 v = make_float4(vp.x+vs.x, vp.y+vs.y, vp.z+vs.z, vp.w+vs.w);
  float4 pv = *(const float4*)(pos + t*D_MODEL + d);
  v.x += pv.x; v.y += pv.y; v.z += pv.z; v.w += pv.w;
  *(float4*)(zf + (size_t)blockIdx.x*D_MODEL + d) = v;
}

// ---------------- plain LN ----------------
__global__ __launch_bounds__(256) void ln_kernel(
    const float* __restrict__ z, const float* __restrict__ gam, const float* __restrict__ bet,
    _Float16* __restrict__ out)
{
  int row = blockIdx.x;
  int tid = threadIdx.x;
  int d = tid * 4;
  float4 v = *(const float4*)(z + (size_t)row*D_MODEL + d);
  ln_row(v, tid, d, gam, bet, out + (size_t)row*D_MODEL + d);
}

// ---------------- attention core (register-tiled) ----------------
__device__ __forceinline__ void attn_core(
    const _Float16* base, float* qs_t, float* ks_t, float* vs, float* sc, int tid)
{
  for (int i = tid; i < TT*DH; i += 256) {
    int t = i >> 6, d2 = i & 63;
    const _Float16* rp = base + (size_t)t*3072 + d2;
    qs_t[d2*68 + t] = (float)rp[0];
    ks_t[d2*68 + t] = (float)rp[1024];
    vs[t*64 + d2]   = (float)rp[2048];
  }
  __syncthreads();
  if (tid < 153) {
    int ti = tid / 9, tj = tid % 9;
    int qi0 = ti*4, kj0 = tj*8;
    float acc[4][8];
    #pragma unroll
    for (int i = 0; i < 4; i++)
      #pragma unroll
      for (int j = 0; j < 8; j++) acc[i][j] = 0.f;
    for (int d2 = 0; d2 < 64; d2++) {
      float4 qv = *(const float4*)(qs_t + d2*68 + qi0);
      float4 k0 = *(const float4*)(ks_t + d2*68 + kj0);
      float4 k1 = *(const float4*)(ks_t + d2*68 + kj0 + 4);
      float q_[4] = {qv.x, qv.y, qv.z, qv.w};
      float k_[8] = {k0.x, k0.y, k0.z, k0.w, k1.x, k1.y, k1.z, k1.w};
      #pragma unroll
      for (int i = 0; i < 4; i++)
        #pragma unroll
        for (int j = 0; j < 8; j++)
          acc[i][j] += q_[i]*k_[j];
    }
    #pragma unroll
    for (int i = 0; i < 4; i++) {
      int qi = qi0 + i;
      if (qi >= TT) continue;
      #pragma unroll
      for (int j = 0; j < 8; j++) {
        int kj = kj0 + j;
        if (kj >= TT) continue;
        float s;
        if (qi >= MEM_LEN && kj >= MEM_LEN && kj > qi) s = -1e9f;
        else s = acc[i][j]*0.125f;
        sc[qi*67 + kj] = s;
      }
    }
  }
  __syncthreads();
  if (tid < TT) {
    float* r = sc + tid*67;
    float m = -1e30f;
    for (int j = 0; j < TT; j++) m = fmaxf(m, r[j]);
    float ssum = 0.f;
    for (int j = 0; j < TT; j++) { float e = __expf(r[j]-m); r[j] = e; ssum += e; }
    float inv = 1.f/ssum;
    for (int j = 0; j < TT; j++) r[j] *= inv;
  }
  __syncthreads();
}

// fallback attn: unified ao[b*TT+qi]
__global__ __launch_bounds__(256) void attn_kernel(
    const _Float16* __restrict__ qkv, _Float16* __restrict__ attn_o)
{
  __shared__ float qs_t[64*68 + 8];
  __shared__ float ks_t[64*68 + 8];
  __shared__ float vs[TT*DH];
  __shared__ float sc[TT*67];
  int bh = blockIdx.x; int b = bh >> 4, h = bh & 15;
  int tid = threadIdx.x;
  attn_core(qkv + (size_t)b*TT*3072 + h*DH, qs_t, ks_t, vs, sc, tid);
  if (tid < 136) {
    int ti = tid >> 3, tj = tid & 7;
    int qi0 = ti*4, d20 = tj*8;
    float acc[4][8];
    #pragma unroll
    for (int i = 0; i < 4; i++)
      #pragma unroll
      for (int j = 0; j < 8; j++) acc[i][j] = 0.f;
    for (int kj = 0; kj < TT; kj++) {
      float a_[4];
      #pragma unroll
      for (int i = 0; i < 4; i++)
        a_[i] = (qi0 + i < TT) ? sc[(qi0+i)*67 + kj] : 0.f;
      float4 v0 = *(const float4*)(vs + kj*64 + d20);
      float4 v1 = *(const float4*)(vs + kj*64 + d20 + 4);
      float v_[8] = {v0.x, v0.y, v0.z, v0.w, v1.x, v1.y, v1.z, v1.w};
      #pragma unroll
      for (int i = 0; i < 4; i++)
        #pragma unroll
        for (int j = 0; j < 8; j++)
          acc[i][j] += a_[i]*v_[j];
    }
    #pragma unroll
    for (int i = 0; i < 4; i++) {
      int qi = qi0 + i;
      if (qi >= TT) continue;
      _Float16* o = attn_o + ((size_t)b*TT + qi)*D_MODEL + h*DH + d20;
      #pragma unroll
      for (int j = 0; j < 8; j++) o[j] = (_Float16)acc[i][j];
    }
  }
}

// tail attn: mem rows -> aoM[b*16+qi], chunk rows -> ao16[(b*LL+c*50+qi-16)]
__global__ __launch_bounds__(256) void attn_split(
    const _Float16* __restrict__ qkv,
    _Float16* __restrict__ aoM, _Float16* __restrict__ ao16, int chunk)
{
  __shared__ float qs_t[64*68 + 8];
  __shared__ float ks_t[64*68 + 8];
  __shared__ float vs[TT*DH];
  __shared__ float sc[TT*67];
  int bh = blockIdx.x; int b = bh >> 4, h = bh & 15;
  int tid = threadIdx.x;
  attn_core(qkv + (size_t)b*TT*3072 + h*DH, qs_t, ks_t, vs, sc, tid);
  if (tid < 136) {
    int ti = tid >> 3, tj = tid & 7;
    int qi0 = ti*4, d20 = tj*8;
    float acc[4][8];
    #pragma unroll
    for (int i = 0; i < 4; i++)
      #pragma unroll
      for (int j = 0; j < 8; j++) acc[i][j] = 0.f;
    for (int kj = 0; kj < TT; kj++) {
      float a_[4];
      #pragma unroll
      for (int i = 0; i < 4; i++)
        a_[i] = (qi0 + i < TT) ? sc[(qi0+i)*67 + kj] : 0.f;
      float4 v0 = *(const float4*)(vs + kj*64 + d20);
      float4 v1 = *(const float4*)(vs + kj*64 + d20 + 4);
      float v_[8] = {v0.x, v0.y, v0.z, v0.w, v1.x, v1.y, v1.z, v1.w};
      #pragma unroll
      for (int i = 0; i < 4; i++)
        #pragma unroll
        for (int j = 0; j < 8; j++)
          acc[i][j] += a_[i]*v_[j];
    }
    #pragma unroll
    for (int i = 0; i < 4; i++) {
      int qi = qi0 + i;
      if (qi >= TT) continue;
      _Float16* o;
      if (qi < MEM_LEN) {
        o = aoM + ((size_t)b*MEM_LEN + qi)*D_MODEL + h*DH + d20;
      } else {
        size_t rg = (size_t)b*LL + (size_t)chunk*CHUNK_LEN + (qi - MEM_LEN);
        o = ao16 + rg*D_MODEL + h*DH + d20;
      }
      #pragma unroll
      for (int j = 0; j < 8; j++) o[j] = (_Float16)acc[i][j];
    }
  }
}

// ---------------- fallback finalize (all rows) ----------------
__global__ __launch_bounds__(256) void finalize_reduce(
    const float* __restrict__ z, const float* __restrict__ p0, const float* __restrict__ p1,
    const float* __restrict__ b2,
    float* __restrict__ enc_out, float* __restrict__ mem,
    _Float16* __restrict__ mcb, float* __restrict__ mcf, int chunk)
{
  int row = blockIdx.x; int b = row / TT, t = row % TT;
  int d = threadIdx.x * 4;
  size_t idx = (size_t)row*D_MODEL + d;
  float4 v  = *(const float4*)(z  + idx);
  float4 a0 = *(const float4*)(p0 + idx);
  float4 a1 = *(const float4*)(p1 + idx);
  float4 bv = *(const float4*)(b2 + d);
  v.x += a0.x + a1.x + bv.x;
  v.y += a0.y + a1.y + bv.y;
  v.z += a0.z + a1.z + bv.z;
  v.w += a0.w + a1.w + bv.w;
  if (t >= MEM_LEN) {
    size_t o = ((size_t)b*LL + (size_t)chunk*CHUNK_LEN + (t - MEM_LEN))*D_MODEL + d;
    *(float4*)(enc_out + o) = v;
  } else {
    size_t mrow = (size_t)b*MEM_LEN + t;
    if (chunk == 0) {
      *(float4*)(mem + mrow*D_MODEL + d) = v;
    } else {
      *(float4*)(mcf + mrow*D_MODEL + d) = v;
      _Float16* o = mcb + mrow*D_MODEL + d;
      o[0] = (_Float16)v.x; o[1] = (_Float16)v.y; o[2] = (_Float16)v.z; o[3] = (_Float16)v.w;
    }
  }
}

// ---------------- tail: finalize mem rows only (compact M=1024) ----------------
__global__ __launch_bounds__(256) void finalize_mem(
    const float* __restrict__ z, const float* __restrict__ p0, const float* __restrict__ p1,
    const float* __restrict__ b2,
    float* __restrict__ mem, _Float16* __restrict__ mcb, float* __restrict__ mcf, int chunk)
{
  int row = blockIdx.x;
  int d = threadIdx.x * 4;
  size_t idx = (size_t)row*D_MODEL + d;
  float4 v  = *(const float4*)(z  + idx);
  float4 a0 = *(const float4*)(p0 + idx);
  float4 a1 = *(const float4*)(p1 + idx);
  float4 bv = *(const float4*)(b2 + d);
  v.x += a0.x + a1.x + bv.x;
  v.y += a0.y + a1.y + bv.y;
  v.z += a0.z + a1.z + bv.z;
  v.w += a0.w + a1.w + bv.w;
  if (chunk == 0) {
    *(float4*)(mem + idx) = v;
  } else {
    *(float4*)(mcf + idx) = v;
    _Float16* o = mcb + idx;
    o[0] = (_Float16)v.x; o[1] = (_Float16)v.y; o[2] = (_Float16)v.z; o[3] = (_Float16)v.w;
  }
}

// ---------------- tail: finalize enc rows of a group ----------------
__global__ __launch_bounds__(256) void finalize_enc(
    const float* __restrict__ zf, const float* __restrict__ p0, const float* __restrict__ p1,
    const float* __restrict__ b2, float* __restrict__ enc, size_t r0)
{
  size_t row = blockIdx.x;
  int d = threadIdx.x * 4;
  size_t idx = row*D_MODEL + d;
  float4 v  = *(const float4*)(zf + idx);
  float4 a0 = *(const float4*)(p0 + idx);
  float4 a1 = *(const float4*)(p1 + idx);
  float4 bv = *(const float4*)(b2 + d);
  v.x += a0.x + a1.x + bv.x;
  v.y += a0.y + a1.y + bv.y;
  v.z += a0.z + a1.z + bv.z;
  v.w += a0.w + a1.w + bv.w;
  *(float4*)(enc + (r0 + row)*D_MODEL + d) = v;
}

// ---------------- copy mem -> output tail ----------------
__global__ __launch_bounds__(256) void copy_mem_kernel(const float* __restrict__ mem,
                                                       float* __restrict__ out) {
  int i = (blockIdx.x * 256 + threadIdx.x) * 4;
  float4 v = *(const float4*)(mem + i);
  *(float4*)(out + i) = v;
}

// ================= GEMM 128x128 (R5 exact: 2-buffer counted vmcnt(4) + XOR swizzle) ==========
#define EPI_QKV   0
#define EPI_RESID 1
#define EPI_RELU  2
#define EPI_PART  3

#define KSLICE 2048

template<int EPI>
__global__ __launch_bounds__(256) void gemm_bt(
    const _Float16* __restrict__ A,
    const _Float16* __restrict__ Bw,
    const float* __restrict__ bias,
    float* __restrict__ zres,      // RESID: residual in/out; PART: partial 0
    _Float16* __restrict__ obf,
    float* __restrict__ p1,        // PART: partial 1
    int K, int lda, int ldo)
{
  __shared__ short As[2][128*32];
  __shared__ short Bs[2][128*32];
  int tid = threadIdx.x;
  int lane = tid & 63, wave = tid >> 6;
  int wr = wave >> 1, wc = wave & 1;
  int tm = blockIdx.y * 128, tn = blockIdx.x * 128;
  f32x4 acc[4][4] = {};
  const short* Ash = (const short*)A;
  const short* Bsh = (const short*)Bw;
  if constexpr (EPI == EPI_PART) {
    Ash += (size_t)blockIdx.z * KSLICE;
    Bsh += (size_t)blockIdx.z * KSLICE;
  }
  int e0 = tid * 8;
  int r0 = e0 >> 5, c0 = e0 & 31;
  int c0s = c0 ^ (((r0 >> 1) & 3) << 3);
  int ko = (lane >> 4) * 8;
  int rr = lane & 15;
  int kos = ko ^ (((rr >> 1) & 3) << 3);

  auto STAGE = [&](int buf, int kt) {
    gload16(Ash + (size_t)(tm +      r0)*lda + kt + c0s, (char*)&As[buf][0] +        wave*1024);
    gload16(Ash + (size_t)(tm + 64 + r0)*lda + kt + c0s, (char*)&As[buf][0] + 4096 + wave*1024);
    gload16(Bsh + (size_t)(tn +      r0)*lda + kt + c0s, (char*)&Bs[buf][0] +        wave*1024);
    gload16(Bsh + (size_t)(tn + 64 + r0)*lda + kt + c0s, (char*)&Bs[buf][0] + 4096 + wave*1024);
  };
  auto COMPUTE = [&](int buf) {
    half8_t af[4], bfr[4];
    #pragma unroll
    for (int m = 0; m < 4; m++)
      af[m] = *(const half8_t*)(&As[buf][(wr*64 + m*16 + rr)*32 + kos]);
    #pragma unroll
    for (int n = 0; n < 4; n++)
      bfr[n] = *(const half8_t*)(&Bs[buf][(wc*64 + n*16 + rr)*32 + kos]);
    #pragma unroll
    for (int m = 0; m < 4; m++)
      #pragma unroll
      for (int n = 0; n < 4; n++)
        acc[m][n] = __builtin_amdgcn_mfma_f32_16x16x32_f16(af[m], bfr[n], acc[m][n], 0, 0, 0);
  };

  STAGE(0, 0);
  int cur = 0;
  for (int kt = 32; kt < K; kt += 32) {
    STAGE(cur ^ 1, kt);
    asm volatile("s_waitcnt vmcnt(4)" ::: "memory");
    __builtin_amdgcn_s_barrier();
    COMPUTE(cur);
    asm volatile("" ::: "memory");
    __builtin_amdgcn_s_barrier();
    cur ^= 1;
  }
  asm volatile("s_waitcnt vmcnt(0)" ::: "memory");
  __builtin_amdgcn_s_barrier();
  COMPUTE(cur);

  int rbase = tm + wr*64 + ((lane >> 4) << 2);
  int cbase = tn + wc*64 + (lane & 15);
  float* pp = nullptr;
  if constexpr (EPI == EPI_PART) pp = (blockIdx.z == 0) ? zres : p1;
  #pragma unroll
  for (int nn = 0; nn < 4; nn++) {
    int col = cbase + nn*16;
    float bs = (EPI == EPI_PART) ? 0.f : bias[col];
    #pragma unroll
    for (int m = 0; m < 4; m++) {
      #pragma unroll
      for (int i = 0; i < 4; i++) {
        int r = rbase + m*16 + i;
        float v = acc[m][nn][i] + bs;
        if constexpr (EPI == EPI_QKV) {
          obf[(size_t)r*ldo + col] = (_Float16)v;
        } else if constexpr (EPI == EPI_RESID) {
          zres[(size_t)r*D_MODEL + col] += v;
        } else if constexpr (EPI == EPI_RELU) {
          obf[(size_t)r*ldo + col] = (_Float16)fmaxf(v, 0.f);
        } else { // EPI_PART
          pp[(size_t)r*D_MODEL + col] = v;
        }
      }
    }
  }
}

// ---------------- gate GEMM (R5 exact) ----------------
__global__ __launch_bounds__(256) void gemm_gate64(
    const _Float16* __restrict__ A,
    const _Float16* __restrict__ Bw,
    const float* __restrict__ bias,
    const float* __restrict__ mcf,
    float* __restrict__ mem)
{
  __shared__ short As[64*32];
  __shared__ short Bs[64*32];
  int tid = threadIdx.x;
  int lane = tid & 63, wave = tid >> 6;
  int wr = wave >> 1, wc = wave & 1;
  int tm = blockIdx.y * 64, tn = blockIdx.x * 64;
  f32x4 acc[2][2] = {};
  const short* Ash = (const short*)A;
  const short* Bsh = (const short*)Bw;
  int e0 = tid * 8;
  int r0 = e0 >> 5, c0 = e0 & 31;

  for (int kt = 0; kt < 1024; kt += 32) {
    gload16(Ash + (size_t)(tm + r0)*1024 + kt + c0, (char*)As + wave*1024);
    gload16(Bsh + (size_t)(tn + r0)*1024 + kt + c0, (char*)Bs + wave*1024);
    __syncthreads();
    half8_t af[2], bfr[2];
    int ko = (lane >> 4) * 8;
    int rr = lane & 15;
    #pragma unroll
    for (int m = 0; m < 2; m++)
      af[m] = *(const half8_t*)(As + (wr*32 + m*16 + rr)*32 + ko);
    #pragma unroll
    for (int n = 0; n < 2; n++)
      bfr[n] = *(const half8_t*)(Bs + (wc*32 + n*16 + rr)*32 + ko);
    #pragma unroll
    for (int m = 0; m < 2; m++)
      #pragma unroll
      for (int n = 0; n < 2; n++)
        acc[m][n] = __builtin_amdgcn_mfma_f32_16x16x32_f16(af[m], bfr[n], acc[m][n], 0, 0, 0);
    __syncthreads();
  }

  int rbase = tm + wr*32 + ((lane >> 4) << 2);
  int cbase = tn + wc*32 + (lane & 15);
  #pragma unroll
  for (int n = 0; n < 2; n++) {
    int col = cbase + n*16;
    float bs = bias[col];
    #pragma unroll
    for (int m = 0; m < 2; m++) {
      #pragma unroll
      for (int i = 0; i < 4; i++) {
        int r = rbase + m*16 + i;
        float g = 1.f / (1.f + __expf(-(acc[m][n][i] + bs)));
        size_t mi = (size_t)r*D_MODEL + col;
        mem[mi] = g*mcf[mi] + (1.f - g)*mem[mi];
      }
    }
  }
}

extern "C" void kernel_launch(void* const* d_in, const int* in_sizes, int n_in,
                              void* d_out, int out_size, void* d_ws, size_t ws_size,
                              hipStream_t stream) {
  const int*   in_prob  = (const int*)d_in[0];
  const int*   in_skill = (const int*)d_in[1];
  const float* emb_p    = (const float*)d_in[2];
  const float* emb_s    = (const float*)d_in[3];
  const float* mem_init = (const float*)d_in[4];
  const float* pos      = (const float*)d_in[5];
  const float* w_qkv    = (const float*)d_in[6];
  const float* b_qkv    = (const float*)d_in[7];
  const float* w_out    = (const float*)d_in[8];
  const float* b_out    = (const float*)d_in[9];
  const float* w1       = (const float*)d_in[10];
  const float* b1       = (const float*)d_in[11];
  const float* w2       = (const float*)d_in[12];
  const float* b2       = (const float*)d_in[13];
  const float* g_attn   = (const float*)d_in[14];
  const float* be_attn  = (const float*)d_in[15];
  const float* g_ffn    = (const float*)d_in[16];
  const float* be_ffn   = (const float*)d_in[17];
  const float* w_gate   = (const float*)d_in[18];
  const float* b_gate   = (const float*)d_in[19];

  float* enc_out = (float*)d_out;
  float* mem_out = enc_out + MALLR*D_MODEL;
  _Float16* ao16 = (_Float16*)d_out;       // ao_all scratch inside d_out (tail mode)

  char* ws = (char*)d_ws;
  size_t off = 0;
  auto alloc = [&](size_t bytes) -> char* {
    char* p = ws + off;
    off += (bytes + 255) & ~(size_t)255;
    return p;
  };
  // ---- common buffers (both modes) ----
  _Float16* wqkv_h = (_Float16*)alloc((size_t)3072*1024*2);
  _Float16* wout_h = (_Float16*)alloc((size_t)1024*1024*2);
  _Float16* w1_h   = (_Float16*)alloc((size_t)4096*1024*2);
  _Float16* w2_h   = (_Float16*)alloc((size_t)1024*4096*2);
  _Float16* wgate_h= (_Float16*)alloc((size_t)1024*1024*2);
  _Float16* zn     = (_Float16*)alloc((size_t)MTOK*D_MODEL*2);
  _Float16* qkv    = (_Float16*)alloc((size_t)MTOK*3072*2);
  _Float16* mcb    = (_Float16*)alloc((size_t)MROW*D_MODEL*2);
  float*    mem    = (float*)alloc((size_t)MROW*D_MODEL*4);
  float*    mcf    = (float*)alloc((size_t)MROW*D_MODEL*4);
  size_t union_base = off;

  // ---- choose mode / group size ----
  auto rnd = [](size_t b) { return (b + 255) & ~(size_t)255; };
  const size_t tm_fixed =
      rnd((size_t)MROW*D_MODEL*4) +   // z_mem
      rnd((size_t)MROW*D_MODEL*2) +   // ao_mem
      rnd((size_t)MROW*D_MODEL*2) +   // hb_mem
      rnd((size_t)MROW*4096*2) +      // fh_mem
      rnd((size_t)MROW*D_MODEL*4) +   // p0m
      rnd((size_t)MROW*D_MODEL*4);    // p1m
  auto gr_bytes = [&](size_t GR) {
    return rnd(GR*D_MODEL*4) + rnd(GR*D_MODEL*2) + rnd(GR*4096*2)
         + rnd(GR*D_MODEL*4) + rnd(GR*D_MODEL*4);   // zf, hbR, fhR, p0R, p1R
  };
  const size_t fb_bytes =
      rnd((size_t)MTOK*D_MODEL*4) + rnd((size_t)MTOK*D_MODEL*2) +
      rnd((size_t)MTOK*D_MODEL*2) + rnd((size_t)MTOK*4096*2) +
      rnd((size_t)MTOK*D_MODEL*4) + rnd((size_t)MTOK*D_MODEL*4);
  size_t GR = 0;
  const size_t cand[3] = {16000, 6400, 3200};
  for (int i = 0; i < 3; i++) {
    if (union_base + tm_fixed + gr_bytes(cand[i]) <= ws_size) { GR = cand[i]; break; }
  }
  bool tailmode = (GR != 0);
  if (!tailmode && union_base + fb_bytes > ws_size) return;  // nothing fits

  // weights -> fp16
  f2h_kernel<<<(3072*1024)/1024, 256, 0, stream>>>(w_qkv, wqkv_h, 3072*1024);
  f2h_kernel<<<(1024*1024)/1024, 256, 0, stream>>>(w_out, wout_h, 1024*1024);
  f2h_kernel<<<(4096*1024)/1024, 256, 0, stream>>>(w1, w1_h, 4096*1024);
  f2h_kernel<<<(1024*4096)/1024, 256, 0, stream>>>(w2, w2_h, 1024*4096);
  f2h_kernel<<<(1024*1024)/1024, 256, 0, stream>>>(w_gate, wgate_h, 1024*1024);

  if (tailmode) {
    float*    z_mem = (float*)alloc((size_t)MROW*D_MODEL*4);
    _Float16* ao_m  = (_Float16*)alloc((size_t)MROW*D_MODEL*2);
    _Float16* hb_m  = (_Float16*)alloc((size_t)MROW*D_MODEL*2);
    _Float16* fh_m  = (_Float16*)alloc((size_t)MROW*4096*2);
    float*    p0m   = (float*)alloc((size_t)MROW*D_MODEL*4);
    float*    p1m   = (float*)alloc((size_t)MROW*D_MODEL*4);
    float*    zf    = (float*)alloc(GR*D_MODEL*4);
    _Float16* hbR   = (_Float16*)alloc(GR*D_MODEL*2);
    _Float16* fhR   = (_Float16*)alloc(GR*4096*2);
    float*    p0R   = (float*)alloc(GR*D_MODEL*4);
    float*    p1R   = (float*)alloc(GR*D_MODEL*4);

    // ---- serial chunk loop: mem-path only; chunk ao -> d_out scratch ----
    for (int c = 0; c < NCHUNK; c++) {
      const float* msrc = (c == 0) ? mem_init : mem;
      int mbs = (c == 0) ? 0 : MEM_LEN*D_MODEL;
      build_z_ln_lite<<<MTOK, 256, 0, stream>>>(in_prob, in_skill, emb_p, emb_s,
                                                msrc, mbs, pos, g_attn, be_attn, z_mem, zn, c);
      gemm_bt<EPI_QKV><<<dim3(3072/128, MTOK/128), 256, 0, stream>>>(
          zn, wqkv_h, b_qkv, nullptr, qkv, nullptr, 1024, 1024, 3072);
      attn_split<<<BB*N_HEADS, 256, 0, stream>>>(qkv, ao_m, ao16, c);
      gemm_bt<EPI_RESID><<<dim3(1024/128, MROW/128), 256, 0, stream>>>(
          ao_m, wout_h, b_out, z_mem, nullptr, nullptr, 1024, 1024, 1024);
      ln_kernel<<<MROW, 256, 0, stream>>>(z_mem, g_ffn, be_ffn, hb_m);
      gemm_bt<EPI_RELU><<<dim3(4096/128, MROW/128), 256, 0, stream>>>(
          hb_m, w1_h, b1, nullptr, fh_m, nullptr, 1024, 1024, 4096);
      gemm_bt<EPI_PART><<<dim3(1024/128, MROW/128, 2), 256, 0, stream>>>(
          fh_m, w2_h, nullptr, p0m, nullptr, p1m, KSLICE, 4096, 1024);
      finalize_mem<<<MROW, 256, 0, stream>>>(z_mem, p0m, p1m, b2, mem, mcb, mcf, c);
      if (c > 0) {
        gemm_gate64<<<dim3(1024/64, 1024/64), 256, 0, stream>>>(
            mcb, wgate_h, b_gate, mcf, mem);
      }
    }

    // ---- batched chunk-row tail, DESCENDING groups (enc writes never clobber unread ao) ----
    int ngroups = (int)(MALLR / GR);
    for (int g = ngroups - 1; g >= 0; --g) {
      size_t r0 = (size_t)g * GR;
      build_zbase_group<<<(int)GR, 256, 0, stream>>>(in_prob, in_skill, emb_p, emb_s,
                                                     pos, zf, r0);
      gemm_bt<EPI_RESID><<<dim3(1024/128, (int)(GR/128)), 256, 0, stream>>>(
          ao16 + r0*D_MODEL, wout_h, b_out, zf, nullptr, nullptr, 1024, 1024, 1024);
      ln_kernel<<<(int)GR, 256, 0, stream>>>(zf, g_ffn, be_ffn, hbR);
      gemm_bt<EPI_RELU><<<dim3(4096/128, (int)(GR/128)), 256, 0, stream>>>(
          hbR, w1_h, b1, nullptr, fhR, nullptr, 1024, 1024, 4096);
      gemm_bt<EPI_PART><<<dim3(1024/128, (int)(GR/128), 2), 256, 0, stream>>>(
          fhR, w2_h, nullptr, p0R, nullptr, p1R, KSLICE, 4096, 1024);
      finalize_enc<<<(int)GR, 256, 0, stream>>>(zf, p0R, p1R, b2, enc_out, r0);
    }
  } else {
    // ---- fallback: exact R5 path ----
    float*    z   = (float*)alloc((size_t)MTOK*D_MODEL*4);
    _Float16* ao  = (_Float16*)alloc((size_t)MTOK*D_MODEL*2);
    _Float16* hb  = (_Float16*)alloc((size_t)MTOK*D_MODEL*2);
    _Float16* fh  = (_Float16*)alloc((size_t)MTOK*4096*2);
    float*    p0f = (float*)alloc((size_t)MTOK*D_MODEL*4);
    float*    p1f = (float*)alloc((size_t)MTOK*D_MODEL*4);
    for (int c = 0; c < NCHUNK; c++) {
      const float* msrc = (c == 0) ? mem_init : mem;
      int mbs = (c == 0) ? 0 : MEM_LEN*D_MODEL;
      build_z_ln<<<MTOK, 256, 0, stream>>>(in_prob, in_skill, emb_p, emb_s,
                                           msrc, mbs, pos, g_attn, be_attn, z, zn, c);
      gemm_bt<EPI_QKV><<<dim3(3072/128, MTOK/128), 256, 0, stream>>>(
          zn, wqkv_h, b_qkv, nullptr, qkv, nullptr, 1024, 1024, 3072);
      attn_kernel<<<BB*N_HEADS, 256, 0, stream>>>(qkv, ao);
      gemm_bt<EPI_RESID><<<dim3(1024/128, MTOK/128), 256, 0, stream>>>(
          ao, wout_h, b_out, z, nullptr, nullptr, 1024, 1024, 1024);
      ln_kernel<<<MTOK, 256, 0, stream>>>(z, g_ffn, be_ffn, hb);
      gemm_bt<EPI_RELU><<<dim3(4096/128, MTOK/128), 256, 0, stream>>>(
          hb, w1_h, b1, nullptr, fh, nullptr, 1024, 1024, 4096);
      gemm_bt<EPI_PART><<<dim3(1024/128, MTOK/128, 2), 256, 0, stream>>>(
          fh, w2_h, nullptr, p0f, nullptr, p1f, KSLICE, 4096, 1024);
      finalize_reduce<<<MTOK, 256, 0, stream>>>(z, p0f, p1f, b2,
                                                enc_out, mem, mcb, mcf, c);
      if (c > 0) {
        gemm_gate64<<<dim3(1024/64, 1024/64), 256, 0, stream>>>(
            mcb, wgate_h, b_gate, mcf, mem);
      }
    }
  }
  copy_mem_kernel<<<(MROW*D_MODEL)/1024, 256, 0, stream>>>(mem, mem_out);
}

// Round 10
// 11711.035 us; speedup vs baseline: 1.1183x; 1.1183x over previous
//
#include <hip/hip_runtime.h>
#include <hip/hip_bf16.h>

#define D_MODEL 1024
#define N_HEADS 16
#define DH 64
#define CHUNK_LEN 50
#define MEM_LEN 16
#define TT 66            // MEM_LEN + CHUNK_LEN
#define BB 64
#define LL 2000
#define NCHUNK 40
#define MTOK (BB*TT)     // 4224

typedef _Float16 half8_t __attribute__((ext_vector_type(8)));
typedef __attribute__((ext_vector_type(4))) float f32x4;

typedef __attribute__((address_space(1))) const void GVoid;
typedef __attribute__((address_space(3))) void LVoid;

__device__ __forceinline__ void gload16(const void* g, void* l) {
  __builtin_amdgcn_global_load_lds((GVoid*)g, (LVoid*)l, 16, 0, 0);
}

// ---------------- weight fp32 -> fp16 ----------------
__global__ __launch_bounds__(256) void f2h_kernel(const float* __restrict__ in,
                                                  _Float16* __restrict__ out, int n) {
  int i = (blockIdx.x * 256 + threadIdx.x) * 4;
  if (i < n) {
    float4 v = *(const float4*)(in + i);
    out[i+0] = (_Float16)v.x;
    out[i+1] = (_Float16)v.y;
    out[i+2] = (_Float16)v.z;
    out[i+3] = (_Float16)v.w;
  }
}

// ---------------- build z (gather + mem + pos) fused with LN1 ----------------
__global__ __launch_bounds__(256) void build_z_ln(
    const int* __restrict__ in_prob, const int* __restrict__ in_skill,
    const float* __restrict__ emb_p, const float* __restrict__ emb_s,
    const float* __restrict__ mem_src, int mem_bstride,
    const float* __restrict__ pos,
    const float* __restrict__ gam, const float* __restrict__ bet,
    float* __restrict__ z, _Float16* __restrict__ zn, int chunk)
{
  int row = blockIdx.x;                 // 0..MTOK-1
  int b = row / TT, t = row % TT;
  int tid = threadIdx.x;
  int d = tid * 4;
  float4 v;
  if (t < MEM_LEN) {
    v = *(const float4*)(mem_src + (size_t)b*mem_bstride + t*D_MODEL + d);
  } else {
    int tok = chunk*CHUNK_LEN + (t - MEM_LEN);
    int p = in_prob[b*LL + tok];
    int s = in_skill[b*LL + tok];
    float4 vp = *(const float4*)(emb_p + (size_t)p*D_MODEL + d);
    float4 vs = *(const float4*)(emb_s + (size_t)s*D_MODEL + d);
    v = make_float4(vp.x+vs.x, vp.y+vs.y, vp.z+vs.z, vp.w+vs.w);
  }
  float4 pv = *(const float4*)(pos + t*D_MODEL + d);
  v.x += pv.x; v.y += pv.y; v.z += pv.z; v.w += pv.w;
  *(float4*)(z + (size_t)row*D_MODEL + d) = v;
  float sum = v.x+v.y+v.z+v.w;
  float sq  = v.x*v.x+v.y*v.y+v.z*v.z+v.w*v.w;
  #pragma unroll
  for (int off = 32; off; off >>= 1) {
    sum += __shfl_down(sum, off, 64);
    sq  += __shfl_down(sq,  off, 64);
  }
  __shared__ float rs_[4], rq_[4];
  int wave = tid >> 6, lane = tid & 63;
  if (lane == 0) { rs_[wave] = sum; rq_[wave] = sq; }
  __syncthreads();
  sum = rs_[0]+rs_[1]+rs_[2]+rs_[3];
  sq  = rq_[0]+rq_[1]+rq_[2]+rq_[3];
  float mu  = sum * (1.0f/D_MODEL);
  float var = sq  * (1.0f/D_MODEL) - mu*mu;
  float rstd = rsqrtf(var + 1e-5f);
  float4 gv = *(const float4*)(gam + d);
  float4 bv = *(const float4*)(bet + d);
  _Float16* o = zn + (size_t)row*D_MODEL + d;
  o[0] = (_Float16)((v.x-mu)*rstd*gv.x + bv.x);
  o[1] = (_Float16)((v.y-mu)*rstd*gv.y + bv.y);
  o[2] = (_Float16)((v.z-mu)*rstd*gv.z + bv.z);
  o[3] = (_Float16)((v.w-mu)*rstd*gv.w + bv.w);
}

// ---------------- plain LN (z fp32 -> fp16 out) ----------------
__global__ __launch_bounds__(256) void ln_kernel(
    const float* __restrict__ z, const float* __restrict__ gam, const float* __restrict__ bet,
    _Float16* __restrict__ out)
{
  int row = blockIdx.x;
  int tid = threadIdx.x;
  int d = tid * 4;
  float4 v = *(const float4*)(z + (size_t)row*D_MODEL + d);
  float sum = v.x+v.y+v.z+v.w;
  float sq  = v.x*v.x+v.y*v.y+v.z*v.z+v.w*v.w;
  #pragma unroll
  for (int off = 32; off; off >>= 1) {
    sum += __shfl_down(sum, off, 64);
    sq  += __shfl_down(sq,  off, 64);
  }
  __shared__ float rs_[4], rq_[4];
  int wave = tid >> 6, lane = tid & 63;
  if (lane == 0) { rs_[wave] = sum; rq_[wave] = sq; }
  __syncthreads();
  sum = rs_[0]+rs_[1]+rs_[2]+rs_[3];
  sq  = rq_[0]+rq_[1]+rq_[2]+rq_[3];
  float mu  = sum * (1.0f/D_MODEL);
  float var = sq  * (1.0f/D_MODEL) - mu*mu;
  float rstd = rsqrtf(var + 1e-5f);
  float4 gv = *(const float4*)(gam + d);
  float4 bv = *(const float4*)(bet + d);
  _Float16* o = out + (size_t)row*D_MODEL + d;
  o[0] = (_Float16)((v.x-mu)*rstd*gv.x + bv.x);
  o[1] = (_Float16)((v.y-mu)*rstd*gv.y + bv.y);
  o[2] = (_Float16)((v.z-mu)*rstd*gv.z + bv.z);
  o[3] = (_Float16)((v.w-mu)*rstd*gv.w + bv.w);
}

// ---------------- attention (per b,h block), register-tiled ----------------
__global__ __launch_bounds__(256) void attn_kernel(
    const _Float16* __restrict__ qkv, _Float16* __restrict__ attn_o)
{
  __shared__ float qs_t[64*68 + 8];
  __shared__ float ks_t[64*68 + 8];
  __shared__ float vs[TT*DH];
  __shared__ float sc[TT*67];
  int bh = blockIdx.x; int b = bh >> 4, h = bh & 15;
  int tid = threadIdx.x;
  const _Float16* base = qkv + (size_t)b*TT*3072 + h*DH;
  for (int i = tid; i < TT*DH; i += 256) {
    int t = i >> 6, d2 = i & 63;
    const _Float16* rp = base + (size_t)t*3072 + d2;
    qs_t[d2*68 + t] = (float)rp[0];
    ks_t[d2*68 + t] = (float)rp[1024];
    vs[t*64 + d2]   = (float)rp[2048];
  }
  __syncthreads();
  if (tid < 153) {
    int ti = tid / 9, tj = tid % 9;
    int qi0 = ti*4, kj0 = tj*8;
    float acc[4][8];
    #pragma unroll
    for (int i = 0; i < 4; i++)
      #pragma unroll
      for (int j = 0; j < 8; j++) acc[i][j] = 0.f;
    for (int d2 = 0; d2 < 64; d2++) {
      float4 qv = *(const float4*)(qs_t + d2*68 + qi0);
      float4 k0 = *(const float4*)(ks_t + d2*68 + kj0);
      float4 k1 = *(const float4*)(ks_t + d2*68 + kj0 + 4);
      float q_[4] = {qv.x, qv.y, qv.z, qv.w};
      float k_[8] = {k0.x, k0.y, k0.z, k0.w, k1.x, k1.y, k1.z, k1.w};
      #pragma unroll
      for (int i = 0; i < 4; i++)
        #pragma unroll
        for (int j = 0; j < 8; j++)
          acc[i][j] += q_[i]*k_[j];
    }
    #pragma unroll
    for (int i = 0; i < 4; i++) {
      int qi = qi0 + i;
      if (qi >= TT) continue;
      #pragma unroll
      for (int j = 0; j < 8; j++) {
        int kj = kj0 + j;
        if (kj >= TT) continue;
        float s;
        if (qi >= MEM_LEN && kj >= MEM_LEN && kj > qi) s = -1e9f;
        else s = acc[i][j]*0.125f;
        sc[qi*67 + kj] = s;
      }
    }
  }
  __syncthreads();
  if (tid < TT) {
    float* r = sc + tid*67;
    float m = -1e30f;
    for (int j = 0; j < TT; j++) m = fmaxf(m, r[j]);
    float ssum = 0.f;
    for (int j = 0; j < TT; j++) { float e = __expf(r[j]-m); r[j] = e; ssum += e; }
    float inv = 1.f/ssum;
    for (int j = 0; j < TT; j++) r[j] *= inv;
  }
  __syncthreads();
  if (tid < 136) {
    int ti = tid >> 3, tj = tid & 7;
    int qi0 = ti*4, d20 = tj*8;
    float acc[4][8];
    #pragma unroll
    for (int i = 0; i < 4; i++)
      #pragma unroll
      for (int j = 0; j < 8; j++) acc[i][j] = 0.f;
    for (int kj = 0; kj < TT; kj++) {
      float a_[4];
      #pragma unroll
      for (int i = 0; i < 4; i++)
        a_[i] = (qi0 + i < TT) ? sc[(qi0+i)*67 + kj] : 0.f;
      float4 v0 = *(const float4*)(vs + kj*64 + d20);
      float4 v1 = *(const float4*)(vs + kj*64 + d20 + 4);
      float v_[8] = {v0.x, v0.y, v0.z, v0.w, v1.x, v1.y, v1.z, v1.w};
      #pragma unroll
      for (int i = 0; i < 4; i++)
        #pragma unroll
        for (int j = 0; j < 8; j++)
          acc[i][j] += a_[i]*v_[j];
    }
    #pragma unroll
    for (int i = 0; i < 4; i++) {
      int qi = qi0 + i;
      if (qi >= TT) continue;
      _Float16* o = attn_o + ((size_t)b*TT + qi)*D_MODEL + h*DH + d20;
      #pragma unroll
      for (int j = 0; j < 8; j++) o[j] = (_Float16)acc[i][j];
    }
  }
}

// ---------------- finalize+reduce ----------------
__global__ __launch_bounds__(256) void finalize_reduce(
    const float* __restrict__ z, const float* __restrict__ p0, const float* __restrict__ p1,
    const float* __restrict__ b2,
    float* __restrict__ enc_out, float* __restrict__ mem,
    _Float16* __restrict__ mcb, float* __restrict__ mcf, int chunk)
{
  int row = blockIdx.x; int b = row / TT, t = row % TT;
  int d = threadIdx.x * 4;
  size_t idx = (size_t)row*D_MODEL + d;
  float4 v  = *(const float4*)(z  + idx);
  float4 a0 = *(const float4*)(p0 + idx);
  float4 a1 = *(const float4*)(p1 + idx);
  float4 bv = *(const float4*)(b2 + d);
  v.x += a0.x + a1.x + bv.x;
  v.y += a0.y + a1.y + bv.y;
  v.z += a0.z + a1.z + bv.z;
  v.w += a0.w + a1.w + bv.w;
  if (t >= MEM_LEN) {
    size_t o = ((size_t)b*LL + (size_t)chunk*CHUNK_LEN + (t - MEM_LEN))*D_MODEL + d;
    *(float4*)(enc_out + o) = v;
  } else {
    size_t mrow = (size_t)b*MEM_LEN + t;
    if (chunk == 0) {
      *(float4*)(mem + mrow*D_MODEL + d) = v;
    } else {
      *(float4*)(mcf + mrow*D_MODEL + d) = v;
      _Float16* o = mcb + mrow*D_MODEL + d;
      o[0] = (_Float16)v.x;
      o[1] = (_Float16)v.y;
      o[2] = (_Float16)v.z;
      o[3] = (_Float16)v.w;
    }
  }
}

// ---------------- copy mem -> output tail ----------------
__global__ __launch_bounds__(256) void copy_mem_kernel(const float* __restrict__ mem,
                                                       float* __restrict__ out) {
  int i = (blockIdx.x * 256 + threadIdx.x) * 4;
  float4 v = *(const float4*)(mem + i);
  *(float4*)(out + i) = v;
}

// ================= GEMM 128x128: R5 pipeline + T1 XCD-aware block swizzle =================
// T1: remap hw block id so each XCD owns a contiguous set of N-column tiles ->
// per-XCD B-panel (~0.8 MB) stays resident in its private 4MB L2; A streams once.
// Bijective iff nwg%8==0 (true for all grids here: 792/264/1056/528); else identity.
#define EPI_QKV   0
#define EPI_RESID 1
#define EPI_RELU  2
#define EPI_PART  3

#define KSLICE 2048

template<int EPI>
__global__ __launch_bounds__(256) void gemm_bt(
    const _Float16* __restrict__ A,
    const _Float16* __restrict__ Bw,
    const float* __restrict__ bias,
    float* __restrict__ zres,      // RESID: residual in/out; PART: partial 0
    _Float16* __restrict__ obf,
    float* __restrict__ p1,        // PART: partial 1
    int K, int lda, int ldo)
{
  __shared__ short As[2][128*32];
  __shared__ short Bs[2][128*32];
  int tid = threadIdx.x;
  int lane = tid & 63, wave = tid >> 6;
  int wr = wave >> 1, wc = wave & 1;
  // ---- T1 XCD swizzle ----
  int gx = gridDim.x, gy = gridDim.y;
  int nwg = gx * gy;
  int bx, by;
  if (nwg & 7) {
    bx = blockIdx.x; by = blockIdx.y;
  } else {
    int hwbid = blockIdx.y * gx + blockIdx.x;     // hw dispatch order (x fastest)
    int cpx = nwg >> 3;
    int logical = (hwbid & 7) * cpx + (hwbid >> 3);  // XCD k owns logical [k*cpx, (k+1)*cpx)
    bx = logical / gy;                             // N-column-major chunking
    by = logical % gy;
  }
  int tm = by * 128, tn = bx * 128;
  f32x4 acc[4][4] = {};
  const short* Ash = (const short*)A;
  const short* Bsh = (const short*)Bw;
  if constexpr (EPI == EPI_PART) {
    Ash += (size_t)blockIdx.z * KSLICE;
    Bsh += (size_t)blockIdx.z * KSLICE;
  }
  int e0 = tid * 8;
  int r0 = e0 >> 5, c0 = e0 & 31;
  int c0s = c0 ^ (((r0 >> 1) & 3) << 3);   // pre-swizzled global source column
  int ko = (lane >> 4) * 8;
  int rr = lane & 15;
  int kos = ko ^ (((rr >> 1) & 3) << 3);   // read-side XOR

  auto STAGE = [&](int buf, int kt) {
    gload16(Ash + (size_t)(tm +      r0)*lda + kt + c0s, (char*)&As[buf][0] +        wave*1024);
    gload16(Ash + (size_t)(tm + 64 + r0)*lda + kt + c0s, (char*)&As[buf][0] + 4096 + wave*1024);
    gload16(Bsh + (size_t)(tn +      r0)*lda + kt + c0s, (char*)&Bs[buf][0] +        wave*1024);
    gload16(Bsh + (size_t)(tn + 64 + r0)*lda + kt + c0s, (char*)&Bs[buf][0] + 4096 + wave*1024);
  };
  auto COMPUTE = [&](int buf) {
    half8_t af[4], bfr[4];
    #pragma unroll
    for (int m = 0; m < 4; m++)
      af[m] = *(const half8_t*)(&As[buf][(wr*64 + m*16 + rr)*32 + kos]);
    #pragma unroll
    for (int n = 0; n < 4; n++)
      bfr[n] = *(const half8_t*)(&Bs[buf][(wc*64 + n*16 + rr)*32 + kos]);
    #pragma unroll
    for (int m = 0; m < 4; m++)
      #pragma unroll
      for (int n = 0; n < 4; n++)
        acc[m][n] = __builtin_amdgcn_mfma_f32_16x16x32_f16(af[m], bfr[n], acc[m][n], 0, 0, 0);
  };

  STAGE(0, 0);
  int cur = 0;
  for (int kt = 32; kt < K; kt += 32) {
    STAGE(cur ^ 1, kt);
    asm volatile("s_waitcnt vmcnt(4)" ::: "memory");   // current buf landed; next stays in flight
    __builtin_amdgcn_s_barrier();
    COMPUTE(cur);
    asm volatile("" ::: "memory");
    __builtin_amdgcn_s_barrier();
    cur ^= 1;
  }
  asm volatile("s_waitcnt vmcnt(0)" ::: "memory");
  __builtin_amdgcn_s_barrier();
  COMPUTE(cur);

  int rbase = tm + wr*64 + ((lane >> 4) << 2);
  int cbase = tn + wc*64 + (lane & 15);
  float* pp = nullptr;
  if constexpr (EPI == EPI_PART) pp = (blockIdx.z == 0) ? zres : p1;
  #pragma unroll
  for (int nn = 0; nn < 4; nn++) {
    int col = cbase + nn*16;
    float bs = (EPI == EPI_PART) ? 0.f : bias[col];
    #pragma unroll
    for (int m = 0; m < 4; m++) {
      #pragma unroll
      for (int i = 0; i < 4; i++) {
        int r = rbase + m*16 + i;
        float v = acc[m][nn][i] + bs;
        if constexpr (EPI == EPI_QKV) {
          obf[(size_t)r*ldo + col] = (_Float16)v;
        } else if constexpr (EPI == EPI_RESID) {
          zres[(size_t)r*D_MODEL + col] += v;
        } else if constexpr (EPI == EPI_RELU) {
          obf[(size_t)r*ldo + col] = (_Float16)fmaxf(v, 0.f);
        } else { // EPI_PART
          pp[(size_t)r*D_MODEL + col] = v;
        }
      }
    }
  }
}

// ---------------- gate GEMM: 64x64 tiles + T1 swizzle ----------------
__global__ __launch_bounds__(256) void gemm_gate64(
    const _Float16* __restrict__ A,
    const _Float16* __restrict__ Bw,
    const float* __restrict__ bias,
    const float* __restrict__ mcf,
    float* __restrict__ mem)
{
  __shared__ short As[64*32];
  __shared__ short Bs[64*32];
  int tid = threadIdx.x;
  int lane = tid & 63, wave = tid >> 6;
  int wr = wave >> 1, wc = wave & 1;
  int gx = gridDim.x, gy = gridDim.y;
  int nwg = gx * gy;
  int bx, by;
  if (nwg & 7) {
    bx = blockIdx.x; by = blockIdx.y;
  } else {
    int hwbid = blockIdx.y * gx + blockIdx.x;
    int cpx = nwg >> 3;
    int logical = (hwbid & 7) * cpx + (hwbid >> 3);
    bx = logical / gy;
    by = logical % gy;
  }
  int tm = by * 64, tn = bx * 64;
  f32x4 acc[2][2] = {};
  const short* Ash = (const short*)A;
  const short* Bsh = (const short*)Bw;
  int e0 = tid * 8;
  int r0 = e0 >> 5, c0 = e0 & 31;

  for (int kt = 0; kt < 1024; kt += 32) {
    gload16(Ash + (size_t)(tm + r0)*1024 + kt + c0, (char*)As + wave*1024);
    gload16(Bsh + (size_t)(tn + r0)*1024 + kt + c0, (char*)Bs + wave*1024);
    __syncthreads();
    half8_t af[2], bfr[2];
    int ko = (lane >> 4) * 8;
    int rr = lane & 15;
    #pragma unroll
    for (int m = 0; m < 2; m++)
      af[m] = *(const half8_t*)(As + (wr*32 + m*16 + rr)*32 + ko);
    #pragma unroll
    for (int n = 0; n < 2; n++)
      bfr[n] = *(const half8_t*)(Bs + (wc*32 + n*16 + rr)*32 + ko);
    #pragma unroll
    for (int m = 0; m < 2; m++)
      #pragma unroll
      for (int n = 0; n < 2; n++)
        acc[m][n] = __builtin_amdgcn_mfma_f32_16x16x32_f16(af[m], bfr[n], acc[m][n], 0, 0, 0);
    __syncthreads();
  }

  int rbase = tm + wr*32 + ((lane >> 4) << 2);
  int cbase = tn + wc*32 + (lane & 15);
  #pragma unroll
  for (int n = 0; n < 2; n++) {
    int col = cbase + n*16;
    float bs = bias[col];
    #pragma unroll
    for (int m = 0; m < 2; m++) {
      #pragma unroll
      for (int i = 0; i < 4; i++) {
        int r = rbase + m*16 + i;
        float g = 1.f / (1.f + __expf(-(acc[m][n][i] + bs)));
        size_t mi = (size_t)r*D_MODEL + col;
        mem[mi] = g*mcf[mi] + (1.f - g)*mem[mi];
      }
    }
  }
}

extern "C" void kernel_launch(void* const* d_in, const int* in_sizes, int n_in,
                              void* d_out, int out_size, void* d_ws, size_t ws_size,
                              hipStream_t stream) {
  const int*   in_prob  = (const int*)d_in[0];
  const int*   in_skill = (const int*)d_in[1];
  const float* emb_p    = (const float*)d_in[2];
  const float* emb_s    = (const float*)d_in[3];
  const float* mem_init = (const float*)d_in[4];
  const float* pos      = (const float*)d_in[5];
  const float* w_qkv    = (const float*)d_in[6];
  const float* b_qkv    = (const float*)d_in[7];
  const float* w_out    = (const float*)d_in[8];
  const float* b_out    = (const float*)d_in[9];
  const float* w1       = (const float*)d_in[10];
  const float* b1       = (const float*)d_in[11];
  const float* w2       = (const float*)d_in[12];
  const float* b2       = (const float*)d_in[13];
  const float* g_attn   = (const float*)d_in[14];
  const float* be_attn  = (const float*)d_in[15];
  const float* g_ffn    = (const float*)d_in[16];
  const float* be_ffn   = (const float*)d_in[17];
  const float* w_gate   = (const float*)d_in[18];
  const float* b_gate   = (const float*)d_in[19];

  float* enc_out = (float*)d_out;
  float* mem_out = enc_out + (size_t)BB*LL*D_MODEL;

  char* ws = (char*)d_ws;
  size_t off = 0;
  auto alloc = [&](size_t bytes) -> char* {
    char* p = ws + off;
    off += (bytes + 255) & ~(size_t)255;
    return p;
  };
  _Float16* wqkv_h = (_Float16*)alloc((size_t)3072*1024*2);
  _Float16* wout_h = (_Float16*)alloc((size_t)1024*1024*2);
  _Float16* w1_h   = (_Float16*)alloc((size_t)4096*1024*2);
  _Float16* w2_h   = (_Float16*)alloc((size_t)1024*4096*2);
  _Float16* wgate_h= (_Float16*)alloc((size_t)1024*1024*2);
  float*    z      = (float*)alloc((size_t)MTOK*D_MODEL*4);
  _Float16* zn     = (_Float16*)alloc((size_t)MTOK*D_MODEL*2);
  _Float16* qkv    = (_Float16*)alloc((size_t)MTOK*3072*2);
  _Float16* ao     = (_Float16*)alloc((size_t)MTOK*D_MODEL*2);
  _Float16* hb     = (_Float16*)alloc((size_t)MTOK*D_MODEL*2);
  _Float16* fh     = (_Float16*)alloc((size_t)MTOK*4096*2);
  _Float16* mcb    = (_Float16*)alloc((size_t)1024*1024*2);
  float*    mem    = (float*)alloc((size_t)1024*1024*4);
  float*    mcf    = (float*)alloc((size_t)1024*1024*4);
  float*    part0  = (float*)alloc((size_t)MTOK*D_MODEL*4);
  float*    part1  = (float*)alloc((size_t)MTOK*D_MODEL*4);
  if (off > ws_size) return;

  // weights -> fp16 (once per call)
  f2h_kernel<<<(3072*1024)/1024, 256, 0, stream>>>(w_qkv, wqkv_h, 3072*1024);
  f2h_kernel<<<(1024*1024)/1024, 256, 0, stream>>>(w_out, wout_h, 1024*1024);
  f2h_kernel<<<(4096*1024)/1024, 256, 0, stream>>>(w1, w1_h, 4096*1024);
  f2h_kernel<<<(1024*4096)/1024, 256, 0, stream>>>(w2, w2_h, 1024*4096);
  f2h_kernel<<<(1024*1024)/1024, 256, 0, stream>>>(w_gate, wgate_h, 1024*1024);

  for (int c = 0; c < NCHUNK; c++) {
    const float* msrc = (c == 0) ? mem_init : mem;
    int mbs = (c == 0) ? 0 : MEM_LEN*D_MODEL;
    build_z_ln<<<MTOK, 256, 0, stream>>>(in_prob, in_skill, emb_p, emb_s,
                                         msrc, mbs, pos, g_attn, be_attn, z, zn, c);
    gemm_bt<EPI_QKV><<<dim3(3072/128, MTOK/128), 256, 0, stream>>>(
        zn, wqkv_h, b_qkv, nullptr, qkv, nullptr, 1024, 1024, 3072);
    attn_kernel<<<BB*N_HEADS, 256, 0, stream>>>(qkv, ao);
    gemm_bt<EPI_RESID><<<dim3(1024/128, MTOK/128), 256, 0, stream>>>(
        ao, wout_h, b_out, z, nullptr, nullptr, 1024, 1024, 1024);
    ln_kernel<<<MTOK, 256, 0, stream>>>(z, g_ffn, be_ffn, hb);
    gemm_bt<EPI_RELU><<<dim3(4096/128, MTOK/128), 256, 0, stream>>>(
        hb, w1_h, b1, nullptr, fh, nullptr, 1024, 1024, 4096);
    gemm_bt<EPI_PART><<<dim3(1024/128, MTOK/128, 2), 256, 0, stream>>>(
        fh, w2_h, nullptr, part0, nullptr, part1, KSLICE, 4096, 1024);
    finalize_reduce<<<MTOK, 256, 0, stream>>>(z, part0, part1, b2,
                                              enc_out, mem, mcb, mcf, c);
    if (c > 0) {
      gemm_gate64<<<dim3(1024/64, 1024/64), 256, 0, stream>>>(
          mcb, wgate_h, b_gate, mcf, mem);
    }
  }
  copy_mem_kernel<<<(1024*1024)/1024, 256, 0, stream>>>(mem, mem_out);
}